// Round 17
// baseline (162.727 us; speedup 1.0000x reference)
//
#include <hip/hip_runtime.h>
#include <hip/hip_bf16.h>

#define DIMK 512
#define NROWS 131072

typedef __bf16 bf16x8 __attribute__((ext_vector_type(8)));
typedef float f32x4 __attribute__((ext_vector_type(4)));

// fragment-ordered bf16 W: [nblk(32)][kchunk(64)][l15(16)][8k]
__device__ __attribute__((aligned(16))) unsigned short g_Wt2[DIMK * DIMK];

static __device__ __forceinline__ void gload_lds16(const void* g, void* l) {
    __builtin_amdgcn_global_load_lds(
        (const __attribute__((address_space(1))) void*)(unsigned long)(g),
        (__attribute__((address_space(3))) void*)(unsigned long)(l), 16, 0, 0);
}

static __device__ __forceinline__ unsigned short f2bf(float f) {
    unsigned u = __builtin_bit_cast(unsigned, f);
    u += 0x7FFFu + ((u >> 16) & 1u);
    return (unsigned short)(u >> 16);
}

// ---------- W[k][n] fp32 -> fragment-ordered bf16 ----------
__global__ void wprep_kernel(const float* __restrict__ W) {
    __shared__ float tile[64][65];
    const int bk = blockIdx.x & 7;
    const int bn = blockIdx.x >> 3;
    const int t = threadIdx.x;       // 256
    const int rl = t >> 2;
    const int ch = t & 3;

    const float* src = W + (bk * 64 + rl) * DIMK + bn * 64 + ch * 16;
    float4 v[4];
#pragma unroll
    for (int i = 0; i < 4; i++) v[i] = reinterpret_cast<const float4*>(src)[i];
#pragma unroll
    for (int i = 0; i < 4; i++) {
        tile[rl][ch * 16 + i * 4 + 0] = v[i].x;
        tile[rl][ch * 16 + i * 4 + 1] = v[i].y;
        tile[rl][ch * 16 + i * 4 + 2] = v[i].z;
        tile[rl][ch * 16 + i * 4 + 3] = v[i].w;
    }
    __syncthreads();

    unsigned short o[16];
#pragma unroll
    for (int i = 0; i < 16; i++) o[i] = f2bf(tile[ch * 16 + i][rl]);
    const int nblk = bn * 4 + (rl >> 4);
    const int kchunk = bk * 8 + ch * 2;
    unsigned short* dst = g_Wt2 + nblk * 8192 + kchunk * 128 + (rl & 15) * 8;
    *reinterpret_cast<uint4*>(dst) = *reinterpret_cast<uint4*>(&o[0]);
    *reinterpret_cast<uint4*>(dst + 128) = *reinterpret_cast<uint4*>(&o[8]);
}

// ---------- fused dense GEMM + mask-select, one pass over X ----------
// block = 64 rows x 512 cols; 8 waves (1x8), per-wave 64x64 frags;
// A fp32 via gload_lds (16KB) + reg converts; B bf16 frag-ordered (64KB);
// unmasked rows copied to out per-phase from the LDS A-tile (no X re-read).
__global__ __launch_bounds__(512, 4)
void fused_kernel(const float* __restrict__ X, const void* __restrict__ maskp,
                  float* __restrict__ out) {
    __shared__ __attribute__((aligned(16))) float Als[4096];            // 16 KB [g4][c8][j16][8f]
    __shared__ __attribute__((aligned(16))) unsigned short Bls[32768];  // 64 KB [nblk32][c8][j16][8h]

    const int bid = blockIdx.x;          // 0..2047
    const long row0 = (long)bid * 64;
    const int t = threadIdx.x;           // 512
    const int lane = t & 63;
    const int wid = t >> 6;              // 0..7 = column-wave
    const int l15 = lane & 15, lhi = lane >> 4;

    // ---- mask dtype detect (flag word parked in Als[0]) ----
    if (t == 0) ((int*)Als)[0] = 0;
    __syncthreads();
    {   // window in-bounds under byte/int32/int64 interpretations
        unsigned w = ((const unsigned*)maskp)[(bid & 63) * 512 + t];
        int fl = (w > 1u) ? 1 : 0;
        if ((t & 1) && w != 0u) fl |= 2;
        if (fl) atomicOr((int*)Als, fl);
    }
    __syncthreads();
    const int flg = ((int*)Als)[0];
    const int md = (flg & 1) ? 0 : ((flg & 2) ? 1 : 2);

    // ---- 64-bit rowmask via ballot (uniform per wave, lives in SGPRs) ----
    bool pred;
    {
        const long r = row0 + lane;
        if (md == 0)      pred = ((const unsigned char*)maskp)[r] != 0;
        else if (md == 1) pred = ((const int*)maskp)[r] != 0;
        else              pred = ((const unsigned*)maskp)[2 * r] != 0;
    }
    const unsigned long long rowmask = __ballot(pred);
    __syncthreads();   // all waves done with Als[0] before staging overwrites

    // ---- staging descriptors ----
    // A: wave stages 16-row group ag = wid>>1, instrs i = (wid&1)*2 + {0,1};
    // instr i covers c in {2i,2i+1}: lane -> (c=2i+(lane>>5), j=(lane>>1)&15, h=lane&1)
    const int ag = wid >> 1;
    const float* asrc[2];
    float* adst[2];
#pragma unroll
    for (int i2 = 0; i2 < 2; i2++) {
        const int i = (wid & 1) * 2 + i2;
        const int c = 2 * i + (lane >> 5);
        const int j = (lane >> 1) & 15;
        const int h = lane & 1;
        asrc[i2] = X + (row0 + ag * 16 + j) * DIMK + c * 8 + h * 4;
        adst[i2] = Als + ag * 1024 + i * 256;   // wave-uniform; HW adds lane*16B
    }
    // B: wave stages nblks wid*4 + {0..3}, 2 instrs (1KB) each
    const unsigned short* bsrc = g_Wt2 + (long)(wid * 4) * 8192 + lane * 8;
    unsigned short* bdst = Bls + (wid * 4) * 1024;

    f32x4 acc[4][4] = {};
    const int colb = wid * 64;
    const unsigned aro = lhi * 128 + l15 * 8;                     // + m*1024 + s*512
    const unsigned bro = (wid * 4) * 1024 + lhi * 128 + l15 * 8;  // + n*1024 + s*512

#pragma unroll 1
    for (int kt = 0; kt < 8; kt++) {
#pragma unroll
        for (int i2 = 0; i2 < 2; i2++)
            gload_lds16(asrc[i2] + kt * 64, adst[i2]);
#pragma unroll
        for (int nb = 0; nb < 4; nb++)
#pragma unroll
            for (int i = 0; i < 2; i++)
                gload_lds16(bsrc + nb * 8192 + kt * 1024 + i * 512,
                            bdst + nb * 1024 + i * 512);
        __syncthreads();   // drains vmcnt(0): tiles resident

#pragma unroll
        for (int s = 0; s < 2; s++) {
            bf16x8 bfr[4];
#pragma unroll
            for (int n = 0; n < 4; n++)
                bfr[n] = *reinterpret_cast<const bf16x8*>(Bls + bro + n * 1024 + s * 512);
#pragma unroll
            for (int m = 0; m < 4; m++) {
                const float* ap = Als + m * 1024 + s * 512 + aro;
                f32x4 u = *reinterpret_cast<const f32x4*>(ap);
                f32x4 v = *reinterpret_cast<const f32x4*>(ap + 4);
                bf16x8 a;
                a[0] = (__bf16)u[0]; a[1] = (__bf16)u[1];
                a[2] = (__bf16)u[2]; a[3] = (__bf16)u[3];
                a[4] = (__bf16)v[0]; a[5] = (__bf16)v[1];
                a[6] = (__bf16)v[2]; a[7] = (__bf16)v[3];
#pragma unroll
                for (int n = 0; n < 4; n++)
                    acc[m][n] = __builtin_amdgcn_mfma_f32_16x16x32_bf16(
                        a, bfr[n], acc[m][n], 0, 0, 0);
            }
        }

        // unmasked rows: copy this k-slab from LDS A-tile (wave owns rows wid*8..+8)
#pragma unroll
        for (int q = 0; q < 2; q++) {
            const int jr = wid * 8 + q * 4 + lhi;
            if (!((rowmask >> jr) & 1ull)) {
                const float* sp = Als + (jr >> 4) * 1024 + (l15 >> 1) * 128
                                + (jr & 15) * 8 + (l15 & 1) * 4;
                f32x4 val = *reinterpret_cast<const f32x4*>(sp);
                __builtin_nontemporal_store(val,
                    reinterpret_cast<f32x4*>(out + (row0 + jr) * DIMK + kt * 64) + l15);
            }
        }
        __syncthreads();   // reads done before next overwrite
    }

    // ---- epilogue: masked rows only; C/D col = l15, row = lhi*4 + reg ----
#pragma unroll
    for (int m = 0; m < 4; m++) {
#pragma unroll
        for (int j = 0; j < 4; j++) {
            const int rl_ = m * 16 + lhi * 4 + j;
            if ((rowmask >> rl_) & 1ull) {
                float* orow = out + (row0 + rl_) * DIMK + colb;
#pragma unroll
                for (int n = 0; n < 4; n++)
                    orow[n * 16 + l15] = acc[m][n][j];
            }
        }
    }
}

extern "C" void kernel_launch(void* const* d_in, const int* in_sizes, int n_in,
                              void* d_out, int out_size, void* d_ws, size_t ws_size,
                              hipStream_t stream) {
    const float* X = (const float*)d_in[0];
    const void* mask = d_in[1];
    const float* W = (const float*)d_in[2];
    float* out = (float*)d_out;

    hipLaunchKernelGGL(wprep_kernel, dim3(64), dim3(256), 0, stream, W);
    hipLaunchKernelGGL(fused_kernel, dim3(NROWS / 64), dim3(512), 0, stream, X, mask, out);
}